// Round 1
// baseline (711.237 us; speedup 1.0000x reference)
//
#include <hip/hip_runtime.h>
#include <cmath>

// Problem constants (from reference): B=1024, IN=1024, OUT=1024, K=100
#define KSAMP 100
#define DIN   1024
#define DOUT  1024
#define DB    1024

// ---------------------------------------------------------------------------
// Kernel 1: W_eff[i][j] = mean_k(eps[k][i][j]) * softplus(ws[i][j]) + wm[i][j]
// Pure HBM stream of eps (419 MB). float4 per thread, coalesced per k-slice.
// ---------------------------------------------------------------------------
__global__ __launch_bounds__(256) void weff_kernel(
    const float4* __restrict__ eps,
    const float4* __restrict__ wm,
    const float4* __restrict__ ws,
    float4* __restrict__ weff)
{
    const int idx = blockIdx.x * blockDim.x + threadIdx.x;   // 0..262143
    const int n4 = (DIN * DOUT) / 4;

    float sx = 0.f, sy = 0.f, sz = 0.f, sw = 0.f;
    const float4* p = eps + idx;
    #pragma unroll 4
    for (int k = 0; k < KSAMP; ++k) {
        float4 e = p[(size_t)k * n4];
        sx += e.x; sy += e.y; sz += e.z; sw += e.w;
    }

    float4 s = ws[idx];
    float4 m = wm[idx];
    const float invK = 1.0f / (float)KSAMP;

    // softplus(v) = max(v,0) + log1p(exp(-|v|))  (numerically stable)
    float spx = fmaxf(s.x, 0.f) + log1pf(expf(-fabsf(s.x)));
    float spy = fmaxf(s.y, 0.f) + log1pf(expf(-fabsf(s.y)));
    float spz = fmaxf(s.z, 0.f) + log1pf(expf(-fabsf(s.z)));
    float spw = fmaxf(s.w, 0.f) + log1pf(expf(-fabsf(s.w)));

    float4 o;
    o.x = fmaf(sx * invK, spx, m.x);
    o.y = fmaf(sy * invK, spy, m.y);
    o.z = fmaf(sz * invK, spz, m.z);
    o.w = fmaf(sw * invK, spw, m.w);
    weff[idx] = o;
}

// ---------------------------------------------------------------------------
// Kernel 2: C[B,OUT] = x[B,IN] @ W_eff[IN,OUT], fp32 (no fp32 MFMA on CDNA4).
// 128x128 block tile, 256 threads, 8x8 per-thread micro-tile, BK=8.
// Split-K x4 (grid.z) so grid = 8*8*4 = 256 blocks -> all 256 CUs covered.
// Epilogue: fp32 atomicAdd into zeroed C.
// ---------------------------------------------------------------------------
#define BM 128
#define BN 128
#define BK 8
#define KSPLIT 4

__global__ __launch_bounds__(256) void sgemm_splitk(
    const float* __restrict__ A,   // x      [DB,  DIN]
    const float* __restrict__ B,   // W_eff  [DIN, DOUT]
    float* __restrict__ C)         // out    [DB,  DOUT], pre-zeroed
{
    __shared__ float As[BK][BM];   // A tile, transposed (k-major)
    __shared__ float Bs[BK][BN];

    const int bx = blockIdx.x, by = blockIdx.y, kz = blockIdx.z;
    const int tid = threadIdx.x;
    const int tx = tid & 15;       // 0..15 -> 8 cols each
    const int ty = tid >> 4;       // 0..15 -> 8 rows each

    const int kc = DIN / KSPLIT;   // 256
    const int k_begin = kz * kc;
    const int k_end   = k_begin + kc;

    // A-tile load map: 128 rows x 8 k, one float4 per thread along k
    const int arow = tid >> 1;          // 0..127
    const int acol = (tid & 1) * 4;     // 0 or 4
    // B-tile load map: 8 k-rows x 128 cols, one float4 per thread along n
    const int brow = tid >> 5;          // 0..7
    const int bcol = (tid & 31) * 4;    // 0..124

    float acc[8][8];
    #pragma unroll
    for (int i = 0; i < 8; ++i)
        #pragma unroll
        for (int j = 0; j < 8; ++j) acc[i][j] = 0.f;

    for (int k0 = k_begin; k0 < k_end; k0 += BK) {
        // Global loads into registers first (overlaps with previous compute)
        float4 a = *(const float4*)&A[(size_t)(by * BM + arow) * DIN + k0 + acol];
        float4 b = *(const float4*)&B[(size_t)(k0 + brow) * DOUT + bx * BN + bcol];

        __syncthreads();   // previous iteration's LDS reads complete
        As[acol + 0][arow] = a.x;
        As[acol + 1][arow] = a.y;
        As[acol + 2][arow] = a.z;
        As[acol + 3][arow] = a.w;
        *(float4*)&Bs[brow][bcol] = b;
        __syncthreads();   // LDS tile visible

        #pragma unroll
        for (int kk = 0; kk < BK; ++kk) {
            float4 a0 = *(const float4*)&As[kk][ty * 8];
            float4 a1 = *(const float4*)&As[kk][ty * 8 + 4];
            float4 b0 = *(const float4*)&Bs[kk][tx * 8];
            float4 b1 = *(const float4*)&Bs[kk][tx * 8 + 4];
            const float ar[8] = {a0.x, a0.y, a0.z, a0.w, a1.x, a1.y, a1.z, a1.w};
            const float br[8] = {b0.x, b0.y, b0.z, b0.w, b1.x, b1.y, b1.z, b1.w};
            #pragma unroll
            for (int i = 0; i < 8; ++i)
                #pragma unroll
                for (int j = 0; j < 8; ++j)
                    acc[i][j] = fmaf(ar[i], br[j], acc[i][j]);
        }
    }

    // Epilogue: accumulate split-K partials
    #pragma unroll
    for (int i = 0; i < 8; ++i) {
        const int r = by * BM + ty * 8 + i;
        float* crow = &C[(size_t)r * DOUT + bx * BN + tx * 8];
        #pragma unroll
        for (int j = 0; j < 8; ++j)
            atomicAdd(&crow[j], acc[i][j]);
    }
}

// ---------------------------------------------------------------------------
extern "C" void kernel_launch(void* const* d_in, const int* in_sizes, int n_in,
                              void* d_out, int out_size, void* d_ws, size_t ws_size,
                              hipStream_t stream) {
    const float* x   = (const float*)d_in[0];   // [1024,1024]
    const float* eps = (const float*)d_in[1];   // [100,1024,1024]
    const float* wm  = (const float*)d_in[2];   // [1024,1024]
    const float* ws  = (const float*)d_in[3];   // [1024,1024]
    float* out  = (float*)d_out;                // [1024,1024]
    float* weff = (float*)d_ws;                 // 4 MB scratch

    // d_out is poisoned 0xAA before every call; zero it for the atomic epilogue.
    hipMemsetAsync(d_out, 0, (size_t)out_size * sizeof(float), stream);

    weff_kernel<<<(DIN * DOUT / 4) / 256, 256, 0, stream>>>(
        (const float4*)eps, (const float4*)wm, (const float4*)ws, (float4*)weff);

    sgemm_splitk<<<dim3(DOUT / BN, DB / BM, KSPLIT), 256, 0, stream>>>(x, weff, out);
}

// Round 3
// 580.753 us; speedup vs baseline: 1.2247x; 1.2247x over previous
//
#include <hip/hip_runtime.h>
#include <cmath>

// Problem constants: B=1024, IN=1024, OUT=1024, K=100
#define KSAMP 100
#define DIN   1024
#define DOUT  1024
#define DB    1024

typedef float f4 __attribute__((ext_vector_type(4)));  // native vec for nontemporal

// ---------------------------------------------------------------------------
// Kernel 1: W_eff[i][j] = mean_k(eps[k][i][j]) * softplus(ws[i][j]) + wm[i][j]
// Pure HBM stream of eps (419 MB). One float4 per thread, marches k.
// ---------------------------------------------------------------------------
__global__ __launch_bounds__(256) void weff_kernel(
    const f4* __restrict__ eps,
    const f4* __restrict__ wm,
    const f4* __restrict__ ws,
    f4* __restrict__ weff)
{
    const int idx = blockIdx.x * blockDim.x + threadIdx.x;   // 0..262143
    const int n4 = (DIN * DOUT) / 4;

    f4 acc0 = {0.f, 0.f, 0.f, 0.f};
    f4 acc1 = {0.f, 0.f, 0.f, 0.f};
    const f4* p = eps + idx;
    // 100 = 50 x 2; deep unroll -> many loads in flight, two acc chains
    #pragma unroll 10
    for (int k = 0; k < KSAMP; k += 2) {
        f4 e0 = __builtin_nontemporal_load(p);
        f4 e1 = __builtin_nontemporal_load(p + n4);
        p += 2 * n4;
        acc0 += e0;
        acc1 += e1;
    }
    f4 sum = acc0 + acc1;

    f4 s = ws[idx];
    f4 m = wm[idx];
    const float invK = 1.0f / (float)KSAMP;

    // softplus(v) = max(v,0) + log1p(exp(-|v|))  (numerically stable)
    f4 sp;
    sp.x = fmaxf(s.x, 0.f) + log1pf(expf(-fabsf(s.x)));
    sp.y = fmaxf(s.y, 0.f) + log1pf(expf(-fabsf(s.y)));
    sp.z = fmaxf(s.z, 0.f) + log1pf(expf(-fabsf(s.z)));
    sp.w = fmaxf(s.w, 0.f) + log1pf(expf(-fabsf(s.w)));

    f4 o;
    o.x = fmaf(sum.x * invK, sp.x, m.x);
    o.y = fmaf(sum.y * invK, sp.y, m.y);
    o.z = fmaf(sum.z * invK, sp.z, m.z);
    o.w = fmaf(sum.w * invK, sp.w, m.w);
    weff[idx] = o;
}

// ---------------------------------------------------------------------------
// Kernel 2: split-K fp32 GEMM, partials to workspace (no atomics).
// 128x128 tile, 256 threads, 8x8 micro-tile, BK=8, KSPLIT=8 -> 512 blocks
// (2 blocks/CU, 2 waves/SIMD for latency hiding). Next global tile is
// prefetched into registers before the compute loop (overlaps ~900cyc HBM
// latency with the FMA burst).
// ---------------------------------------------------------------------------
#define BM 128
#define BN 128
#define BK 8
#define KSPLIT 8

__global__ __launch_bounds__(256, 2) void sgemm_splitk(
    const float* __restrict__ A,   // x      [DB,  DIN]
    const float* __restrict__ B,   // W_eff  [DIN, DOUT]
    float* __restrict__ P)         // partials [KSPLIT][DB][DOUT]
{
    __shared__ float As[BK][BM];   // k-major (A transposed in LDS)
    __shared__ float Bs[BK][BN];

    const int bx = blockIdx.x, by = blockIdx.y, kz = blockIdx.z;
    const int tid = threadIdx.x;
    const int tx = tid & 15;       // 0..15 -> 8 output cols each
    const int ty = tid >> 4;       // 0..15 -> 8 output rows each

    const int kc = DIN / KSPLIT;   // 128
    const int k_begin = kz * kc;

    // A load map: row = tid>>1 (0..127), kcol = (tid&1)*4
    const int arow = tid >> 1;
    const int acol = (tid & 1) * 4;
    // B load map: krow = tid>>5 (0..7), col = (tid&31)*4
    const int brow = tid >> 5;
    const int bcol = (tid & 31) * 4;

    const float* Aptr = &A[(size_t)(by * BM + arow) * DIN + k_begin + acol];
    const float* Bptr = &B[(size_t)(k_begin + brow) * DOUT + bx * BN + bcol];

    float acc[8][8];
    #pragma unroll
    for (int i = 0; i < 8; ++i)
        #pragma unroll
        for (int j = 0; j < 8; ++j) acc[i][j] = 0.f;

    // Preload first tile
    float4 a = *(const float4*)Aptr;
    float4 b = *(const float4*)Bptr;

    const int niter = kc / BK;     // 16
    for (int it = 0; it < niter; ++it) {
        __syncthreads();           // previous iteration's LDS reads done
        As[acol + 0][arow] = a.x;
        As[acol + 1][arow] = a.y;
        As[acol + 2][arow] = a.z;
        As[acol + 3][arow] = a.w;
        *(float4*)&Bs[brow][bcol] = b;
        __syncthreads();           // tile visible

        // Prefetch next tile while computing this one
        if (it + 1 < niter) {
            a = *(const float4*)(Aptr + (it + 1) * BK);
            b = *(const float4*)(Bptr + (size_t)(it + 1) * BK * DOUT);
        }

        #pragma unroll
        for (int kk = 0; kk < BK; ++kk) {
            float4 a0 = *(const float4*)&As[kk][ty * 8];
            float4 a1 = *(const float4*)&As[kk][ty * 8 + 4];
            float4 b0 = *(const float4*)&Bs[kk][tx * 8];
            float4 b1 = *(const float4*)&Bs[kk][tx * 8 + 4];
            const float ar[8] = {a0.x, a0.y, a0.z, a0.w, a1.x, a1.y, a1.z, a1.w};
            const float br[8] = {b0.x, b0.y, b0.z, b0.w, b1.x, b1.y, b1.z, b1.w};
            #pragma unroll
            for (int i = 0; i < 8; ++i)
                #pragma unroll
                for (int j = 0; j < 8; ++j)
                    acc[i][j] = fmaf(ar[i], br[j], acc[i][j]);
        }
    }

    // Plain float4 stores to this split's partial buffer
    float* Pz = P + (size_t)kz * DB * DOUT;
    #pragma unroll
    for (int i = 0; i < 8; ++i) {
        const int r = by * BM + ty * 8 + i;
        float* prow = &Pz[(size_t)r * DOUT + bx * BN + tx * 8];
        *(float4*)&prow[0] = make_float4(acc[i][0], acc[i][1], acc[i][2], acc[i][3]);
        *(float4*)&prow[4] = make_float4(acc[i][4], acc[i][5], acc[i][6], acc[i][7]);
    }
}

// ---------------------------------------------------------------------------
// Kernel 3: sum the KSPLIT partial buffers into d_out.
// ---------------------------------------------------------------------------
__global__ __launch_bounds__(256) void reduce_kernel(
    const f4* __restrict__ P, f4* __restrict__ out)
{
    const int idx = blockIdx.x * blockDim.x + threadIdx.x;  // 0..262143
    const int n4 = (DB * DOUT) / 4;
    f4 s = P[idx];
    #pragma unroll
    for (int z = 1; z < KSPLIT; ++z) {
        s += P[(size_t)z * n4 + idx];
    }
    out[idx] = s;
}

// ---------------------------------------------------------------------------
extern "C" void kernel_launch(void* const* d_in, const int* in_sizes, int n_in,
                              void* d_out, int out_size, void* d_ws, size_t ws_size,
                              hipStream_t stream) {
    const float* x   = (const float*)d_in[0];   // [1024,1024]
    const float* eps = (const float*)d_in[1];   // [100,1024,1024]
    const float* wm  = (const float*)d_in[2];   // [1024,1024]
    const float* ws  = (const float*)d_in[3];   // [1024,1024]

    float* weff     = (float*)d_ws;                          // 4 MB
    float* partials = (float*)d_ws + (size_t)DIN * DOUT;     // 8 x 4 MB

    weff_kernel<<<(DIN * DOUT / 4) / 256, 256, 0, stream>>>(
        (const f4*)eps, (const f4*)wm, (const f4*)ws, (f4*)weff);

    sgemm_splitk<<<dim3(DOUT / BN, DB / BM, KSPLIT), 256, 0, stream>>>(
        x, weff, partials);

    reduce_kernel<<<(DB * DOUT / 4) / 256, 256, 0, stream>>>(
        (const f4*)partials, (f4*)d_out);
}